// Round 1
// baseline (428.119 us; speedup 1.0000x reference)
//
#include <hip/hip_runtime.h>
#include <stdint.h>

typedef float v4f __attribute__((ext_vector_type(4)));
typedef short v8s __attribute__((ext_vector_type(8)));

#define LOG2E 1.44269504088896f

__device__ __forceinline__ unsigned short f2bf(float f) {
    unsigned int u = __float_as_uint(f);
    u += 0x7fffu + ((u >> 16) & 1u);          // RTNE
    return (unsigned short)(u >> 16);
}

// ---------------- elementwise f32 -> bf16 (x4 vectorized) ----------------
__global__ void k_cast_bf16(const float* __restrict__ src,
                            unsigned short* __restrict__ dst, int n4) {
    int i = blockIdx.x * blockDim.x + threadIdx.x;
    int stride = gridDim.x * blockDim.x;
    for (; i < n4; i += stride) {
        float4 v = ((const float4*)src)[i];
        ushort4 o;
        o.x = f2bf(v.x); o.y = f2bf(v.y); o.z = f2bf(v.z); o.w = f2bf(v.w);
        ((ushort4*)dst)[i] = o;
    }
}

// ------------- transpose + cast: src f32 [K][N] -> dst bf16 [N][K] -------------
__global__ void k_transpose_cast(const float* __restrict__ src,
                                 unsigned short* __restrict__ dst, int K, int N) {
    __shared__ unsigned short tile[64][65];
    int kb = blockIdx.y * 64, nb = blockIdx.x * 64;
    int t = threadIdx.x;
    for (int i = 0; i < 16; ++i) {
        int e = t + i * 256;
        int n_l = e & 63, k_l = e >> 6;
        tile[n_l][k_l] = f2bf(src[(size_t)(kb + k_l) * N + nb + n_l]);
    }
    __syncthreads();
    for (int i = 0; i < 16; ++i) {
        int e = t + i * 256;
        int k_l = e & 63, n_l = e >> 6;
        dst[(size_t)(nb + n_l) * K + kb + k_l] = tile[n_l][k_l];
    }
}

// ------------- GEMM: C[M][N] f32 = A[M][K] bf16 @ Bt[N][K] bf16 -------------
// 128x128 tile, BK=32, 4 waves (2x2), each wave 4x4 of 16x16x32 MFMA.
__global__ __launch_bounds__(256) void k_gemm_bt(
    const unsigned short* __restrict__ A,
    const unsigned short* __restrict__ Bt,
    float* __restrict__ C, int M, int N, int K) {
    __shared__ unsigned short Ab[128 * 32];
    __shared__ unsigned short Bb[128 * 32];
    const int t = threadIdx.x;
    const int w = t >> 6, l = t & 63, quad = l >> 4, ln = l & 15;
    const int wm = (w >> 1) * 64, wn = (w & 1) * 64;
    const int mb = blockIdx.y * 128, nb = blockIdx.x * 128;
    const int srow = t >> 2, scol = (t & 3) * 8;

    v4f acc[4][4];
#pragma unroll
    for (int i = 0; i < 4; ++i)
#pragma unroll
        for (int j = 0; j < 4; ++j) acc[i][j] = (v4f){0.f, 0.f, 0.f, 0.f};

    for (int k0 = 0; k0 < K; k0 += 32) {
        __syncthreads();
#pragma unroll
        for (int u = 0; u < 2; ++u) {
            int r = srow + u * 64;
            ((uint4*)Ab)[t + u * 256] =
                *(const uint4*)(A + (size_t)(mb + r) * K + k0 + scol);
            ((uint4*)Bb)[t + u * 256] =
                *(const uint4*)(Bt + (size_t)(nb + r) * K + k0 + scol);
        }
        __syncthreads();
        v8s af[4], bfr[4];
#pragma unroll
        for (int i = 0; i < 4; ++i)
            af[i] = *(const v8s*)&Ab[(wm + i * 16 + ln) * 32 + quad * 8];
#pragma unroll
        for (int j = 0; j < 4; ++j)
            bfr[j] = *(const v8s*)&Bb[(wn + j * 16 + ln) * 32 + quad * 8];
#pragma unroll
        for (int i = 0; i < 4; ++i)
#pragma unroll
            for (int j = 0; j < 4; ++j)
                acc[i][j] = __builtin_amdgcn_mfma_f32_16x16x32_bf16(
                    af[i], bfr[j], acc[i][j], 0, 0, 0);
    }

#pragma unroll
    for (int i = 0; i < 4; ++i) {
        int r0 = mb + wm + i * 16 + quad * 4;
#pragma unroll
        for (int j = 0; j < 4; ++j) {
            int c0 = nb + wn + j * 16 + ln;
#pragma unroll
            for (int r = 0; r < 4; ++r)
                C[(size_t)(r0 + r) * N + c0] = acc[i][j][r];
        }
    }
}

// ------------- RoPE + split: qkv f32 [B*S][3072] -> Q,K [BH][S][64] bf16 (Q pre-scaled),
//               V transposed -> Vt [BH][64][S] bf16 -------------
__global__ void k_rope_split(const float* __restrict__ qkv,
                             unsigned short* __restrict__ Qg,
                             unsigned short* __restrict__ Kg,
                             unsigned short* __restrict__ Vt) {
    __shared__ unsigned short vtile[64][65];
    const int bh = blockIdx.y, sb = blockIdx.x * 64;
    const int b = bh >> 4, h = bh & 15;
    const int t = threadIdx.x;

    for (int i = 0; i < 8; ++i) {
        int e = t + i * 256;               // 0..2047
        int d = e & 31, s_l = e >> 5;
        int s = sb + s_l;
        const float* row = qkv + (size_t)(b * 2048 + s) * 3072 + h * 64;
        float inv = __expf(-(float)d * 0.28782313662425572f);  // 10000^(-d/32)
        float ang = (float)s * inv;
        float sn, cs;
        sincosf(ang, &sn, &cs);
        float q1 = row[d], q2 = row[d + 32];
        float k1 = row[1024 + d], k2 = row[1024 + d + 32];
        size_t qb = (size_t)(bh * 2048 + s) * 64;
        Qg[qb + d]      = f2bf((q1 * cs - q2 * sn) * 0.125f);
        Qg[qb + d + 32] = f2bf((q2 * cs + q1 * sn) * 0.125f);
        Kg[qb + d]      = f2bf(k1 * cs - k2 * sn);
        Kg[qb + d + 32] = f2bf(k2 * cs + k1 * sn);
    }
    for (int i = 0; i < 16; ++i) {
        int e = t + i * 256;               // 0..4095
        int d = e & 63, s_l = e >> 6;
        float v = qkv[(size_t)(b * 2048 + sb + s_l) * 3072 + 2048 + h * 64 + d];
        vtile[d][s_l] = f2bf(v);
    }
    __syncthreads();
    for (int i = 0; i < 16; ++i) {
        int e = t + i * 256;
        int s_l = e & 63, d = e >> 6;
        Vt[(size_t)(bh * 64 + d) * 2048 + sb + s_l] = vtile[d][s_l];
    }
}

// ------------- causal flash attention -------------
// grid (qtile, bh); 4 waves; wave w owns q rows [qbase+16w, qbase+16w+16)
__global__ __launch_bounds__(256) void k_flash(
    const unsigned short* __restrict__ Qg,   // [BH][S][64], pre-scaled 1/8
    const unsigned short* __restrict__ Kg,   // [BH][S][64]
    const unsigned short* __restrict__ Vt,   // [BH][64][S]
    unsigned short* __restrict__ Og) {       // [B*S][1024]
    __shared__ unsigned short P[4][16][64];
    const int bh = blockIdx.y, qt = blockIdx.x;
    const int b = bh >> 4, h = bh & 15;
    const int t = threadIdx.x, w = t >> 6, l = t & 63, quad = l >> 4, ln = l & 15;
    const int qbase = qt * 64;

    const unsigned short* Qp = Qg + (size_t)bh * 2048 * 64;
    const unsigned short* Kp = Kg + (size_t)bh * 2048 * 64;
    const unsigned short* Vp = Vt + (size_t)bh * 64 * 2048;

    const int qrow_frag = qbase + w * 16 + ln;   // A-fragment row (m = lane&15)
    v8s qf0 = *(const v8s*)(Qp + (size_t)qrow_frag * 64 + quad * 8);
    v8s qf1 = *(const v8s*)(Qp + (size_t)qrow_frag * 64 + quad * 8 + 32);

    v4f oacc[4];
#pragma unroll
    for (int dt = 0; dt < 4; ++dt) oacc[dt] = (v4f){0.f, 0.f, 0.f, 0.f};
    float m_run[4], l_run[4];
#pragma unroll
    for (int r = 0; r < 4; ++r) { m_run[r] = -__builtin_inff(); l_run[r] = 0.f; }

    for (int kvb = 0; kvb <= qbase; kvb += 64) {
        // ---- scores S = Q K^T  (C layout: row q = quad*4+r, col kv = kt*16+ln)
        v4f sc[4];
#pragma unroll
        for (int kt = 0; kt < 4; ++kt) {
            sc[kt] = (v4f){0.f, 0.f, 0.f, 0.f};
            const unsigned short* kr =
                Kp + (size_t)(kvb + kt * 16 + ln) * 64 + quad * 8;
            v8s kf0 = *(const v8s*)kr;
            v8s kf1 = *(const v8s*)(kr + 32);
            sc[kt] = __builtin_amdgcn_mfma_f32_16x16x32_bf16(qf0, kf0, sc[kt], 0, 0, 0);
            sc[kt] = __builtin_amdgcn_mfma_f32_16x16x32_bf16(qf1, kf1, sc[kt], 0, 0, 0);
        }
        if (kvb == qbase) {   // only diagonal tile needs masking
            int q0 = qbase + w * 16 + quad * 4;
#pragma unroll
            for (int kt = 0; kt < 4; ++kt) {
                int kv = kvb + kt * 16 + ln;
#pragma unroll
                for (int r = 0; r < 4; ++r)
                    if (kv > q0 + r) sc[kt][r] = -1e30f;
            }
        }
        // ---- online softmax (reduce across the 16 lanes sharing a row-group)
        float alpha[4];
#pragma unroll
        for (int r = 0; r < 4; ++r) {
            float v = fmaxf(fmaxf(sc[0][r], sc[1][r]), fmaxf(sc[2][r], sc[3][r]));
            v = fmaxf(v, __shfl_xor(v, 1));
            v = fmaxf(v, __shfl_xor(v, 2));
            v = fmaxf(v, __shfl_xor(v, 4));
            v = fmaxf(v, __shfl_xor(v, 8));
            float mn = fmaxf(m_run[r], v);
            alpha[r] = exp2f((m_run[r] - mn) * LOG2E);
            m_run[r] = mn;
        }
        float ps[4] = {0.f, 0.f, 0.f, 0.f};
#pragma unroll
        for (int kt = 0; kt < 4; ++kt)
#pragma unroll
            for (int r = 0; r < 4; ++r) {
                float p = exp2f((sc[kt][r] - m_run[r]) * LOG2E);
                sc[kt][r] = p;
                ps[r] += p;
            }
#pragma unroll
        for (int r = 0; r < 4; ++r) {
            float v = ps[r];
            v += __shfl_xor(v, 1); v += __shfl_xor(v, 2);
            v += __shfl_xor(v, 4); v += __shfl_xor(v, 8);
            l_run[r] = l_run[r] * alpha[r] + v;
        }
#pragma unroll
        for (int dt = 0; dt < 4; ++dt)
#pragma unroll
            for (int r = 0; r < 4; ++r) oacc[dt][r] *= alpha[r];

        // ---- P (C layout) -> LDS -> A-operand layout
        __syncthreads();
#pragma unroll
        for (int kt = 0; kt < 4; ++kt)
#pragma unroll
            for (int r = 0; r < 4; ++r)
                P[w][quad * 4 + r][kt * 16 + ln] = f2bf(sc[kt][r]);
        __syncthreads();

        v8s pf0 = *(const v8s*)&P[w][ln][quad * 8];
        v8s pf1 = *(const v8s*)&P[w][ln][quad * 8 + 32];
#pragma unroll
        for (int dt = 0; dt < 4; ++dt) {
            const unsigned short* vr =
                Vp + (size_t)(dt * 16 + ln) * 2048 + kvb + quad * 8;
            v8s vf0 = *(const v8s*)vr;
            v8s vf1 = *(const v8s*)(vr + 32);
            oacc[dt] = __builtin_amdgcn_mfma_f32_16x16x32_bf16(pf0, vf0, oacc[dt], 0, 0, 0);
            oacc[dt] = __builtin_amdgcn_mfma_f32_16x16x32_bf16(pf1, vf1, oacc[dt], 0, 0, 0);
        }
    }

#pragma unroll
    for (int dt = 0; dt < 4; ++dt)
#pragma unroll
        for (int r = 0; r < 4; ++r) {
            int s = qbase + w * 16 + quad * 4 + r;
            float o = oacc[dt][r] / l_run[r];
            Og[(size_t)(b * 2048 + s) * 1024 + h * 64 + dt * 16 + ln] = f2bf(o);
        }
}

extern "C" void kernel_launch(void* const* d_in, const int* in_sizes, int n_in,
                              void* d_out, int out_size, void* d_ws, size_t ws_size,
                              hipStream_t stream) {
    const float* x     = (const float*)d_in[0];
    const float* w_qkv = (const float*)d_in[2];
    const float* w_out = (const float*)d_in[3];
    char* ws = (char*)d_ws;

    unsigned short* xb    = (unsigned short*)(ws);                     //  8 MB
    unsigned short* wqkvT = (unsigned short*)(ws + (size_t)(8 << 20)); //  6 MB
    unsigned short* woutT = (unsigned short*)(ws + (size_t)(14 << 20)); // 2 MB
    float*          qkv   = (float*)(ws + (size_t)(16 << 20));         // 48 MB
    unsigned short* Qg    = (unsigned short*)(ws + (size_t)(64 << 20)); // 8 MB
    unsigned short* Kg    = (unsigned short*)(ws + (size_t)(72 << 20)); // 8 MB
    unsigned short* Vt    = (unsigned short*)(ws + (size_t)(80 << 20)); // 8 MB
    unsigned short* Og    = (unsigned short*)(ws + (size_t)(88 << 20)); // 8 MB

    k_cast_bf16<<<1024, 256, 0, stream>>>(x, xb, 4096 * 1024 / 4);
    k_transpose_cast<<<dim3(48, 16), 256, 0, stream>>>(w_qkv, wqkvT, 1024, 3072);
    k_transpose_cast<<<dim3(16, 16), 256, 0, stream>>>(w_out, woutT, 1024, 1024);
    k_gemm_bt<<<dim3(24, 32), 256, 0, stream>>>(xb, wqkvT, qkv, 4096, 3072, 1024);
    k_rope_split<<<dim3(32, 32), 256, 0, stream>>>(qkv, Qg, Kg, Vt);
    k_flash<<<dim3(32, 32), 256, 0, stream>>>(Qg, Kg, Vt, Og);
    k_gemm_bt<<<dim3(8, 32), 256, 0, stream>>>(Og, woutT, (float*)d_out, 4096, 1024, 1024);
}

// Round 2
// 295.286 us; speedup vs baseline: 1.4498x; 1.4498x over previous
//
#include <hip/hip_runtime.h>
#include <stdint.h>

typedef float v4f __attribute__((ext_vector_type(4)));
typedef short v8s __attribute__((ext_vector_type(8)));

#define LOG2E 1.44269504088896f

__device__ __forceinline__ unsigned short f2bf(float f) {
    unsigned int u = __float_as_uint(f);
    u += 0x7fffu + ((u >> 16) & 1u);          // RTNE
    return (unsigned short)(u >> 16);
}

// ---------------- elementwise f32 -> bf16 (x4 vectorized) ----------------
__global__ void k_cast_bf16(const float* __restrict__ src,
                            unsigned short* __restrict__ dst, int n4) {
    int i = blockIdx.x * blockDim.x + threadIdx.x;
    int stride = gridDim.x * blockDim.x;
    for (; i < n4; i += stride) {
        float4 v = ((const float4*)src)[i];
        ushort4 o;
        o.x = f2bf(v.x); o.y = f2bf(v.y); o.z = f2bf(v.z); o.w = f2bf(v.w);
        ((ushort4*)dst)[i] = o;
    }
}

// ------------- transpose + cast: src f32 [K][N] -> dst bf16 [N][K] -------------
__global__ void k_transpose_cast(const float* __restrict__ src,
                                 unsigned short* __restrict__ dst, int K, int N) {
    __shared__ unsigned short tile[64][65];
    int kb = blockIdx.y * 64, nb = blockIdx.x * 64;
    int t = threadIdx.x;
    for (int i = 0; i < 16; ++i) {
        int e = t + i * 256;
        int n_l = e & 63, k_l = e >> 6;
        tile[n_l][k_l] = f2bf(src[(size_t)(kb + k_l) * N + nb + n_l]);
    }
    __syncthreads();
    for (int i = 0; i < 16; ++i) {
        int e = t + i * 256;
        int k_l = e & 63, n_l = e >> 6;
        dst[(size_t)(nb + n_l) * K + kb + k_l] = tile[n_l][k_l];
    }
}

// ------------- GEMM: C[M][N] f32 = A[M][K] bf16 @ Bt[N][K] bf16 -------------
// 128x128 tile, BK=32, 4 waves (2x2), each wave 4x4 of 16x16x32 MFMA.
__global__ __launch_bounds__(256) void k_gemm_bt(
    const unsigned short* __restrict__ A,
    const unsigned short* __restrict__ Bt,
    float* __restrict__ C, int M, int N, int K) {
    __shared__ unsigned short Ab[128 * 32];
    __shared__ unsigned short Bb[128 * 32];
    const int t = threadIdx.x;
    const int w = t >> 6, l = t & 63, quad = l >> 4, ln = l & 15;
    const int wm = (w >> 1) * 64, wn = (w & 1) * 64;
    const int mb = blockIdx.y * 128, nb = blockIdx.x * 128;
    const int srow = t >> 2, scol = (t & 3) * 8;

    v4f acc[4][4];
#pragma unroll
    for (int i = 0; i < 4; ++i)
#pragma unroll
        for (int j = 0; j < 4; ++j) acc[i][j] = (v4f){0.f, 0.f, 0.f, 0.f};

    for (int k0 = 0; k0 < K; k0 += 32) {
        __syncthreads();
#pragma unroll
        for (int u = 0; u < 2; ++u) {
            int r = srow + u * 64;
            ((uint4*)Ab)[t + u * 256] =
                *(const uint4*)(A + (size_t)(mb + r) * K + k0 + scol);
            ((uint4*)Bb)[t + u * 256] =
                *(const uint4*)(Bt + (size_t)(nb + r) * K + k0 + scol);
        }
        __syncthreads();
        v8s af[4], bfr[4];
#pragma unroll
        for (int i = 0; i < 4; ++i)
            af[i] = *(const v8s*)&Ab[(wm + i * 16 + ln) * 32 + quad * 8];
#pragma unroll
        for (int j = 0; j < 4; ++j)
            bfr[j] = *(const v8s*)&Bb[(wn + j * 16 + ln) * 32 + quad * 8];
#pragma unroll
        for (int i = 0; i < 4; ++i)
#pragma unroll
            for (int j = 0; j < 4; ++j)
                acc[i][j] = __builtin_amdgcn_mfma_f32_16x16x32_bf16(
                    af[i], bfr[j], acc[i][j], 0, 0, 0);
    }

#pragma unroll
    for (int i = 0; i < 4; ++i) {
        int r0 = mb + wm + i * 16 + quad * 4;
#pragma unroll
        for (int j = 0; j < 4; ++j) {
            int c0 = nb + wn + j * 16 + ln;
#pragma unroll
            for (int r = 0; r < 4; ++r)
                C[(size_t)(r0 + r) * N + c0] = acc[i][j][r];
        }
    }
}

// ------------- RoPE + split: qkv f32 [B*S][3072] -> Q,K [BH][S][64] bf16 (Q pre-scaled),
//               V transposed -> Vt [BH][64][S] bf16 -------------
__global__ void k_rope_split(const float* __restrict__ qkv,
                             unsigned short* __restrict__ Qg,
                             unsigned short* __restrict__ Kg,
                             unsigned short* __restrict__ Vt) {
    __shared__ unsigned short vtile[64][65];
    const int bh = blockIdx.y, sb = blockIdx.x * 64;
    const int b = bh >> 4, h = bh & 15;
    const int t = threadIdx.x;

    for (int i = 0; i < 8; ++i) {
        int e = t + i * 256;               // 0..2047
        int d = e & 31, s_l = e >> 5;
        int s = sb + s_l;
        const float* row = qkv + (size_t)(b * 2048 + s) * 3072 + h * 64;
        float inv = __expf(-(float)d * 0.28782313662425572f);  // 10000^(-d/32)
        float ang = (float)s * inv;
        float sn, cs;
        sincosf(ang, &sn, &cs);
        float q1 = row[d], q2 = row[d + 32];
        float k1 = row[1024 + d], k2 = row[1024 + d + 32];
        size_t qb = (size_t)(bh * 2048 + s) * 64;
        Qg[qb + d]      = f2bf((q1 * cs - q2 * sn) * 0.125f);
        Qg[qb + d + 32] = f2bf((q2 * cs + q1 * sn) * 0.125f);
        Kg[qb + d]      = f2bf(k1 * cs - k2 * sn);
        Kg[qb + d + 32] = f2bf(k2 * cs + k1 * sn);
    }
    for (int i = 0; i < 16; ++i) {
        int e = t + i * 256;               // 0..4095
        int d = e & 63, s_l = e >> 6;
        float v = qkv[(size_t)(b * 2048 + sb + s_l) * 3072 + 2048 + h * 64 + d];
        vtile[d][s_l] = f2bf(v);
    }
    __syncthreads();
    for (int i = 0; i < 16; ++i) {
        int e = t + i * 256;
        int s_l = e & 63, d = e >> 6;
        Vt[(size_t)(bh * 64 + d) * 2048 + sb + s_l] = vtile[d][s_l];
    }
}

// ------------- causal flash attention, v2 -------------
// grid (16, 32): block x handles q-tiles {x, 31-x} (33 kv-iters, balanced).
// 4 waves; wave w owns q rows [qbase+16w, qbase+16w+16). No __syncthreads:
// the P round-trip LDS buffer is wave-private. K fragments double-buffered
// in registers (prefetch next kv tile); V loads issued before softmax.
__global__ __launch_bounds__(256) void k_flash(
    const unsigned short* __restrict__ Qg,   // [BH][S][64], pre-scaled 1/8
    const unsigned short* __restrict__ Kg,   // [BH][S][64]
    const unsigned short* __restrict__ Vt,   // [BH][64][S]
    unsigned short* __restrict__ Og) {       // [B*S][1024]
    __shared__ unsigned short P[4][16][64];
    const int bh = blockIdx.y;
    const int b = bh >> 4, h = bh & 15;
    const int t = threadIdx.x, w = t >> 6, l = t & 63, quad = l >> 4, ln = l & 15;

    const unsigned short* Qp = Qg + (size_t)bh * 2048 * 64;
    const unsigned short* Kp = Kg + (size_t)bh * 2048 * 64;
    const unsigned short* Vp = Vt + (size_t)bh * 64 * 2048;

    for (int sel = 0; sel < 2; ++sel) {
        const int qt = sel ? (31 - (int)blockIdx.x) : (int)blockIdx.x;
        const int qbase = qt * 64;
        const int nit = qt + 1;

        const int qrow_frag = qbase + w * 16 + ln;
        v8s qf0 = *(const v8s*)(Qp + (size_t)qrow_frag * 64 + quad * 8);
        v8s qf1 = *(const v8s*)(Qp + (size_t)qrow_frag * 64 + quad * 8 + 32);

        v4f oacc[4];
#pragma unroll
        for (int dt = 0; dt < 4; ++dt) oacc[dt] = (v4f){0.f, 0.f, 0.f, 0.f};
        float m_run[4], l_run[4];
#pragma unroll
        for (int r = 0; r < 4; ++r) { m_run[r] = -__builtin_inff(); l_run[r] = 0.f; }

        v8s kA[8], kB[8];

        auto loadK = [&](int kvb, v8s kf[8]) {
#pragma unroll
            for (int kt = 0; kt < 4; ++kt) {
                const unsigned short* kr =
                    Kp + (size_t)(kvb + kt * 16 + ln) * 64 + quad * 8;
                kf[kt * 2]     = *(const v8s*)kr;
                kf[kt * 2 + 1] = *(const v8s*)(kr + 32);
            }
        };

        auto body = [&](int it, const v8s kf[8]) {
            const int kvb = it * 64;
            // ---- scores (C layout: row q = quad*4+r, col kv = kt*16+ln)
            v4f sc[4];
#pragma unroll
            for (int kt = 0; kt < 4; ++kt) {
                sc[kt] = (v4f){0.f, 0.f, 0.f, 0.f};
                sc[kt] = __builtin_amdgcn_mfma_f32_16x16x32_bf16(qf0, kf[kt * 2], sc[kt], 0, 0, 0);
                sc[kt] = __builtin_amdgcn_mfma_f32_16x16x32_bf16(qf1, kf[kt * 2 + 1], sc[kt], 0, 0, 0);
            }
            // ---- issue V loads early; consumed after softmax
            v8s vf[8];
#pragma unroll
            for (int dt = 0; dt < 4; ++dt) {
                const unsigned short* vr =
                    Vp + (size_t)(dt * 16 + ln) * 2048 + kvb + quad * 8;
                vf[dt * 2]     = *(const v8s*)vr;
                vf[dt * 2 + 1] = *(const v8s*)(vr + 32);
            }
            if (kvb == qbase) {   // only diagonal tile needs masking
                int q0 = qbase + w * 16 + quad * 4;
#pragma unroll
                for (int kt = 0; kt < 4; ++kt) {
                    int kv = kvb + kt * 16 + ln;
#pragma unroll
                    for (int r = 0; r < 4; ++r)
                        if (kv > q0 + r) sc[kt][r] = -1e30f;
                }
            }
            // ---- online softmax over the 16-lane column groups
            float alpha[4];
#pragma unroll
            for (int r = 0; r < 4; ++r) {
                float v = fmaxf(fmaxf(sc[0][r], sc[1][r]), fmaxf(sc[2][r], sc[3][r]));
                v = fmaxf(v, __shfl_xor(v, 1));
                v = fmaxf(v, __shfl_xor(v, 2));
                v = fmaxf(v, __shfl_xor(v, 4));
                v = fmaxf(v, __shfl_xor(v, 8));
                float mn = fmaxf(m_run[r], v);
                alpha[r] = exp2f((m_run[r] - mn) * LOG2E);
                m_run[r] = mn;
            }
            float ps[4] = {0.f, 0.f, 0.f, 0.f};
#pragma unroll
            for (int kt = 0; kt < 4; ++kt)
#pragma unroll
                for (int r = 0; r < 4; ++r) {
                    float p = exp2f((sc[kt][r] - m_run[r]) * LOG2E);
                    sc[kt][r] = p;
                    ps[r] += p;
                }
#pragma unroll
            for (int r = 0; r < 4; ++r) {
                float v = ps[r];
                v += __shfl_xor(v, 1); v += __shfl_xor(v, 2);
                v += __shfl_xor(v, 4); v += __shfl_xor(v, 8);
                l_run[r] = l_run[r] * alpha[r] + v;
            }
#pragma unroll
            for (int dt = 0; dt < 4; ++dt)
#pragma unroll
                for (int r = 0; r < 4; ++r) oacc[dt][r] *= alpha[r];

            // ---- P (C layout) -> wave-private LDS -> A-operand layout
#pragma unroll
            for (int kt = 0; kt < 4; ++kt)
#pragma unroll
                for (int r = 0; r < 4; ++r)
                    P[w][quad * 4 + r][kt * 16 + ln] = f2bf(sc[kt][r]);

            v8s pf0 = *(const v8s*)&P[w][ln][quad * 8];
            v8s pf1 = *(const v8s*)&P[w][ln][quad * 8 + 32];
#pragma unroll
            for (int dt = 0; dt < 4; ++dt) {
                oacc[dt] = __builtin_amdgcn_mfma_f32_16x16x32_bf16(pf0, vf[dt * 2], oacc[dt], 0, 0, 0);
                oacc[dt] = __builtin_amdgcn_mfma_f32_16x16x32_bf16(pf1, vf[dt * 2 + 1], oacc[dt], 0, 0, 0);
            }
        };

        // software-pipelined over kv tiles, K double-buffered (A/B phases)
        loadK(0, kA);
        int it = 0;
        for (;;) {
            if (it + 1 < nit) loadK((it + 1) * 64, kB);
            body(it, kA);
            if (++it >= nit) break;
            if (it + 1 < nit) loadK((it + 1) * 64, kA);
            body(it, kB);
            if (++it >= nit) break;
        }

#pragma unroll
        for (int dt = 0; dt < 4; ++dt)
#pragma unroll
            for (int r = 0; r < 4; ++r) {
                int s = qbase + w * 16 + quad * 4 + r;
                float o = oacc[dt][r] / l_run[r];
                Og[(size_t)(b * 2048 + s) * 1024 + h * 64 + dt * 16 + ln] = f2bf(o);
            }
    }
}

extern "C" void kernel_launch(void* const* d_in, const int* in_sizes, int n_in,
                              void* d_out, int out_size, void* d_ws, size_t ws_size,
                              hipStream_t stream) {
    const float* x     = (const float*)d_in[0];
    const float* w_qkv = (const float*)d_in[2];
    const float* w_out = (const float*)d_in[3];
    char* ws = (char*)d_ws;

    unsigned short* xb    = (unsigned short*)(ws);                     //  8 MB
    unsigned short* wqkvT = (unsigned short*)(ws + (size_t)(8 << 20)); //  6 MB
    unsigned short* woutT = (unsigned short*)(ws + (size_t)(14 << 20)); // 2 MB
    float*          qkv   = (float*)(ws + (size_t)(16 << 20));         // 48 MB
    unsigned short* Qg    = (unsigned short*)(ws + (size_t)(64 << 20)); // 8 MB
    unsigned short* Kg    = (unsigned short*)(ws + (size_t)(72 << 20)); // 8 MB
    unsigned short* Vt    = (unsigned short*)(ws + (size_t)(80 << 20)); // 8 MB
    unsigned short* Og    = (unsigned short*)(ws + (size_t)(88 << 20)); // 8 MB

    k_cast_bf16<<<1024, 256, 0, stream>>>(x, xb, 4096 * 1024 / 4);
    k_transpose_cast<<<dim3(48, 16), 256, 0, stream>>>(w_qkv, wqkvT, 1024, 3072);
    k_transpose_cast<<<dim3(16, 16), 256, 0, stream>>>(w_out, woutT, 1024, 1024);
    k_gemm_bt<<<dim3(24, 32), 256, 0, stream>>>(xb, wqkvT, qkv, 4096, 3072, 1024);
    k_rope_split<<<dim3(32, 32), 256, 0, stream>>>(qkv, Qg, Kg, Vt);
    k_flash<<<dim3(16, 32), 256, 0, stream>>>(Qg, Kg, Vt, Og);
    k_gemm_bt<<<dim3(8, 32), 256, 0, stream>>>(Og, woutT, (float*)d_out, 4096, 1024, 1024);
}